// Round 2
// baseline (3634.254 us; speedup 1.0000x reference)
//
#include <hip/hip_runtime.h>
#include <hip/hip_bf16.h>

// BailingMoeBlock: T=2048 H=1024 NH=8 NKV=2 HD=128 E=16 TOPK=4 NG=4 TKG=2 F=FS=1024
// Round 2: all tensors fp32 (per reference dtypes). fp32 SMEM-tiled GEMMs.
// Compact ws layout (~80 MB peak) with phase-checked aliasing.

#define T_TOK 2048
#define H_DIM 1024
#define NHEAD 8
#define NKVH 2
#define HDIM 128
#define QKV_DIM 1536
#define E_EXP 16
#define TOPKE 4
#define F_DIM 1024
#define FS_DIM 1024
#define NPAIR (T_TOK*TOPKE)
#define EPS_F 1e-6f

#define DEV __device__ __forceinline__

// ---- block reductions (256 threads = 4 waves) ----
DEV float bred_sum(float v, float* sm){
  #pragma unroll
  for(int o=32;o>0;o>>=1) v += __shfl_down(v,o);
  int w = threadIdx.x>>6, l = threadIdx.x&63;
  __syncthreads();                 // protect sm from previous use
  if(l==0) sm[w]=v;
  __syncthreads();
  return sm[0]+sm[1]+sm[2]+sm[3];
}
DEV float bred_max(float v, float* sm){
  #pragma unroll
  for(int o=32;o>0;o>>=1) v = fmaxf(v, __shfl_down(v,o));
  int w = threadIdx.x>>6, l = threadIdx.x&63;
  __syncthreads();
  if(l==0) sm[w]=v;
  __syncthreads();
  return fmaxf(fmaxf(sm[0],sm[1]),fmaxf(sm[2],sm[3]));
}

// ---- K1: resid = hs + residual ; h = rmsnorm(resid, ln1_w) ----
__global__ __launch_bounds__(256) void k_add_rmsnorm(const float* __restrict__ hs,
    const float* __restrict__ rs, const float* __restrict__ w,
    float* __restrict__ resid, float* __restrict__ h){
  int t = blockIdx.x, tid = threadIdx.x;
  __shared__ float sm[4];
  const long base = (long)t*H_DIM;
  float x[4]; float ss = 0.f;
  #pragma unroll
  for(int i=0;i<4;i++){
    int c = tid + i*256;
    float v = hs[base+c] + rs[base+c];
    x[i]=v; resid[base+c]=v; ss += v*v;
  }
  float tot = bred_sum(ss, sm);
  float rms = rsqrtf(tot/(float)H_DIM + EPS_F);
  #pragma unroll
  for(int i=0;i<4;i++){
    int c = tid + i*256;
    h[base+c] = x[i]*rms*w[c];
  }
}

// ---- generic fp32 GEMM: C[MxN] = A[MxK] * B[KxN] (+D) ----
// BM=128 BN=64 BK=16, 256 threads, 8x4 per thread.
// GROUPED: rows in [grpoff[z], grpoff[z+1]); GATHER: A row = rowidx[r].
template<bool GROUPED, bool GATHER, int EPI_ADD>
__global__ __launch_bounds__(256) void gemm_f32(
    const float* __restrict__ A, int lda,
    const float* __restrict__ B, int ldb, long long bstride,
    float* __restrict__ C, int ldc,
    const float* __restrict__ D,
    const int* __restrict__ rowidx, const int* __restrict__ grpoff,
    int Mdense, int K){
  const int z = blockIdx.z;
  const int row_begin = GROUPED ? grpoff[z]   : 0;
  const int row_end   = GROUPED ? grpoff[z+1] : Mdense;
  const int m0 = row_begin + blockIdx.y*128;
  if(m0 >= row_end) return;
  const int n0 = blockIdx.x*64;
  const float* Bz = B + (long long)z*bstride;

  __shared__ float As[16][132];
  __shared__ float Bs[16][65];
  float acc[8][4];
  #pragma unroll
  for(int i=0;i<8;i++)
    #pragma unroll
    for(int j=0;j<4;j++) acc[i][j]=0.f;

  const int tid = threadIdx.x;
  const int tx = tid & 15, ty = tid >> 4;
  const int ar = tid >> 1, ac = (tid & 1)*8;
  const int brr = tid >> 4, bc = (tid & 15)*4;

  const int arow_g = m0 + ar;
  const bool avalid = arow_g < row_end;
  const int arow = avalid ? (GATHER ? rowidx[arow_g] : arow_g) : 0;
  const float* Aptr = A + (long long)arow*lda;

  for(int k0=0;k0<K;k0+=16){
    float4 a0 = make_float4(0,0,0,0), a1 = a0;
    if(avalid){
      a0 = *(const float4*)(Aptr + k0 + ac);
      a1 = *(const float4*)(Aptr + k0 + ac + 4);
    }
    float4 bv = *(const float4*)(Bz + (long long)(k0+brr)*ldb + n0 + bc);
    __syncthreads();
    As[ac+0][ar]=a0.x; As[ac+1][ar]=a0.y; As[ac+2][ar]=a0.z; As[ac+3][ar]=a0.w;
    As[ac+4][ar]=a1.x; As[ac+5][ar]=a1.y; As[ac+6][ar]=a1.z; As[ac+7][ar]=a1.w;
    Bs[brr][bc+0]=bv.x; Bs[brr][bc+1]=bv.y; Bs[brr][bc+2]=bv.z; Bs[brr][bc+3]=bv.w;
    __syncthreads();
    #pragma unroll
    for(int kk=0;kk<16;kk++){
      float a[8], b[4];
      #pragma unroll
      for(int i=0;i<8;i++) a[i]=As[kk][ty*8+i];
      #pragma unroll
      for(int j=0;j<4;j++) b[j]=Bs[kk][tx*4+j];
      #pragma unroll
      for(int i=0;i<8;i++)
        #pragma unroll
        for(int j=0;j<4;j++) acc[i][j] = fmaf(a[i], b[j], acc[i][j]);
    }
  }
  #pragma unroll
  for(int i=0;i<8;i++){
    int r = m0 + ty*8 + i;
    if(r < row_end){
      float* crow = C + (long long)r*ldc + n0 + tx*4;
      float4 v = make_float4(acc[i][0],acc[i][1],acc[i][2],acc[i][3]);
      if(EPI_ADD){
        const float4 d = *(const float4*)(D + (long long)r*ldc + n0 + tx*4);
        v.x+=d.x; v.y+=d.y; v.z+=d.z; v.w+=d.w;
      }
      *(float4*)crow = v;
    }
  }
}

// ---- gate_up GEMM with fused SiLU*up epilogue: act[r][c] = silu(g)*u ----
// B is [K x 2F]; g col = n, u col = n + uoff.
template<bool GROUPED, bool GATHER>
__global__ __launch_bounds__(256) void gemm_gateup(
    const float* __restrict__ A, int lda,
    const float* __restrict__ B, int ldb, long long bstride, int uoff,
    float* __restrict__ Cact, int ldc,
    const int* __restrict__ rowidx, const int* __restrict__ grpoff,
    int Mdense, int K){
  const int z = blockIdx.z;
  const int row_begin = GROUPED ? grpoff[z]   : 0;
  const int row_end   = GROUPED ? grpoff[z+1] : Mdense;
  const int m0 = row_begin + blockIdx.y*128;
  if(m0 >= row_end) return;
  const int n0 = blockIdx.x*64;
  const float* Bz = B + (long long)z*bstride;

  __shared__ float As[16][132];
  __shared__ float Bg[16][65];
  __shared__ float Bu[16][65];
  float accg[8][4], accu[8][4];
  #pragma unroll
  for(int i=0;i<8;i++)
    #pragma unroll
    for(int j=0;j<4;j++){ accg[i][j]=0.f; accu[i][j]=0.f; }

  const int tid = threadIdx.x;
  const int tx = tid & 15, ty = tid >> 4;
  const int ar = tid >> 1, ac = (tid & 1)*8;
  const int brr = tid >> 4, bc = (tid & 15)*4;

  const int arow_g = m0 + ar;
  const bool avalid = arow_g < row_end;
  const int arow = avalid ? (GATHER ? rowidx[arow_g] : arow_g) : 0;
  const float* Aptr = A + (long long)arow*lda;

  for(int k0=0;k0<K;k0+=16){
    float4 a0 = make_float4(0,0,0,0), a1 = a0;
    if(avalid){
      a0 = *(const float4*)(Aptr + k0 + ac);
      a1 = *(const float4*)(Aptr + k0 + ac + 4);
    }
    const float* bp = Bz + (long long)(k0+brr)*ldb + n0 + bc;
    float4 bg4 = *(const float4*)(bp);
    float4 bu4 = *(const float4*)(bp + uoff);
    __syncthreads();
    As[ac+0][ar]=a0.x; As[ac+1][ar]=a0.y; As[ac+2][ar]=a0.z; As[ac+3][ar]=a0.w;
    As[ac+4][ar]=a1.x; As[ac+5][ar]=a1.y; As[ac+6][ar]=a1.z; As[ac+7][ar]=a1.w;
    Bg[brr][bc+0]=bg4.x; Bg[brr][bc+1]=bg4.y; Bg[brr][bc+2]=bg4.z; Bg[brr][bc+3]=bg4.w;
    Bu[brr][bc+0]=bu4.x; Bu[brr][bc+1]=bu4.y; Bu[brr][bc+2]=bu4.z; Bu[brr][bc+3]=bu4.w;
    __syncthreads();
    #pragma unroll
    for(int kk=0;kk<16;kk++){
      float a[8], bg[4], bu2[4];
      #pragma unroll
      for(int i=0;i<8;i++) a[i]=As[kk][ty*8+i];
      #pragma unroll
      for(int j=0;j<4;j++){ bg[j]=Bg[kk][tx*4+j]; bu2[j]=Bu[kk][tx*4+j]; }
      #pragma unroll
      for(int i=0;i<8;i++)
        #pragma unroll
        for(int j=0;j<4;j++){
          accg[i][j] = fmaf(a[i], bg[j],  accg[i][j]);
          accu[i][j] = fmaf(a[i], bu2[j], accu[i][j]);
        }
    }
  }
  #pragma unroll
  for(int i=0;i<8;i++){
    int r = m0 + ty*8 + i;
    if(r < row_end){
      float* crow = Cact + (long long)r*ldc + n0 + tx*4;
      float4 v;
      float g0=accg[i][0], g1=accg[i][1], g2=accg[i][2], g3=accg[i][3];
      v.x = (g0/(1.f+__expf(-g0)))*accu[i][0];
      v.y = (g1/(1.f+__expf(-g1)))*accu[i][1];
      v.z = (g2/(1.f+__expf(-g2)))*accu[i][2];
      v.w = (g3/(1.f+__expf(-g3)))*accu[i][3];
      *(float4*)crow = v;
    }
  }
}

// ---- K3: per-(t,slot) q/k rmsnorm + rope, v copy. 64 threads. ----
// slots 0..7 = q heads, 8..9 = k heads, 10..11 = v heads.
__global__ __launch_bounds__(64) void k_qkv_post(const float* __restrict__ qkv,
    const float* __restrict__ qw, const float* __restrict__ kw,
    const int* __restrict__ pos,
    float* __restrict__ qb, float* __restrict__ kb, float* __restrict__ vb){
  int slot = blockIdx.x, t = blockIdx.y, lane = threadIdx.x;
  const float* x = qkv + (long long)t*QKV_DIM + slot*HDIM;
  float x0 = x[lane], x1 = x[lane+64];
  if(slot < 10){
    float ss = x0*x0 + x1*x1;
    #pragma unroll
    for(int o=32;o>0;o>>=1) ss += __shfl_xor(ss,o);
    float rms = rsqrtf(ss/(float)HDIM + EPS_F);
    const float* w = (slot<8)? qw : kw;
    float n0 = x0*rms*w[lane];
    float n1 = x1*rms*w[lane+64];
    float p = (float)pos[t];
    float invf = __expf(-((float)lane/64.f)*9.210340371976184f); // 10000^{-lane/64}
    float ang = p*invf;
    float s = sinf(ang), c = cosf(ang);
    float o0 = n0*c - n1*s;
    float o1 = n1*c + n0*s;
    float* dst = (slot<8)? (qb + ((long long)slot*T_TOK + t)*HDIM)
                         : (kb + ((long long)(slot-8)*T_TOK + t)*HDIM);
    dst[lane]=o0; dst[lane+64]=o1;
  } else {
    float* dst = vb + ((long long)(slot-10)*T_TOK + t)*HDIM;
    dst[lane]=x0; dst[lane+64]=x1;
  }
}

// ---- K4: causal attention, one block per (head, query) ----
__global__ __launch_bounds__(256) void k_attn(const float* __restrict__ qb,
    const float* __restrict__ kb, const float* __restrict__ vb,
    float* __restrict__ ctx){
  int h = blockIdx.x, t = blockIdx.y, kv = h >> 2;
  __shared__ float sc[T_TOK];
  __shared__ float qs[HDIM];
  __shared__ float red[4];
  __shared__ float cpart[256];
  int tid = threadIdx.x;
  const float* qrow = qb + ((long long)h*T_TOK + t)*HDIM;
  if(tid < HDIM) qs[tid] = qrow[tid];
  __syncthreads();
  const int nk = t + 1;
  const float scale = 0.08838834764831845f;
  float lmax = -1e30f;
  for(int k = tid; k < nk; k += 256){
    const float* krow = kb + ((long long)kv*T_TOK + k)*HDIM;
    float d = 0.f;
    #pragma unroll
    for(int i=0;i<HDIM/4;i++){
      float4 kq = *(const float4*)(krow + i*4);
      d += kq.x*qs[i*4] + kq.y*qs[i*4+1] + kq.z*qs[i*4+2] + kq.w*qs[i*4+3];
    }
    d *= scale;
    sc[k] = d;
    lmax = fmaxf(lmax, d);
  }
  float mx = bred_max(lmax, red);
  float lsum = 0.f;
  for(int k = tid; k < nk; k += 256){
    float p = __expf(sc[k]-mx);
    sc[k] = p; lsum += p;
  }
  float sum = bred_sum(lsum, red);
  float inv = 1.f/sum;
  int d = tid & 127, half = tid >> 7;
  float acc = 0.f;
  for(int k = half; k < nk; k += 2)
    acc += sc[k] * vb[((long long)kv*T_TOK + k)*HDIM + d];
  cpart[tid] = acc;
  __syncthreads();
  if(tid < 128)
    ctx[(long long)t*(NHEAD*HDIM) + h*HDIM + d] = (cpart[tid]+cpart[tid+128])*inv;
}

// ---- K6: h2 = rmsnorm(resid2, ln2_w); also write resid2 to out[1] ----
__global__ __launch_bounds__(256) void k_rms2(const float* __restrict__ r2,
    const float* __restrict__ w, float* __restrict__ h2, float* __restrict__ out2){
  int t = blockIdx.x, tid = threadIdx.x;
  __shared__ float sm[4];
  const long base = (long)t*H_DIM;
  float x[4]; float ss=0.f;
  #pragma unroll
  for(int i=0;i<4;i++){
    int c = tid+i*256;
    float v = r2[base+c];
    x[i]=v; ss += v*v;
    out2[base+c] = v;
  }
  float tot = bred_sum(ss, sm);
  float rms = rsqrtf(tot/(float)H_DIM + EPS_F);
  #pragma unroll
  for(int i=0;i<4;i++){
    int c = tid+i*256;
    h2[base+c] = x[i]*rms*w[c];
  }
}

// ---- K7: router (fp32 exact; precise expf since selection is discontinuous) ----
__global__ __launch_bounds__(256) void k_router(const float* __restrict__ h2,
    const float* __restrict__ gw, const float* __restrict__ eb,
    int* __restrict__ topk_idx, float* __restrict__ topk_w, int* __restrict__ counts){
  int t = blockIdx.x, tid = threadIdx.x;
  int e = tid & 15, seg = tid >> 4;
  const float* hrow = h2 + (long long)t*H_DIM;
  float part = 0.f;
  #pragma unroll 4
  for(int i=0;i<64;i++){
    int hh = seg*64 + i;
    part += hrow[hh]*gw[hh*E_EXP + e];
  }
  __shared__ float pm[16][17];
  __shared__ float sS[16], sfc[16];
  pm[seg][e] = part;
  __syncthreads();
  if(tid < 16){
    float l = 0.f;
    #pragma unroll
    for(int s=0;s<16;s++) l += pm[s][tid];
    float sg = 1.f/(1.f+expf(-l));
    sS[tid]=sg; sfc[tid]=sg+eb[tid];
  }
  __syncthreads();
  if(tid==0){
    float gs[4];
    #pragma unroll
    for(int g=0; g<4; g++){
      float m1=-1e30f, m2=-1e30f;
      for(int j=0;j<4;j++){
        float v=sfc[g*4+j];
        if(v>m1){ m2=m1; m1=v; } else if(v>m2){ m2=v; }
      }
      gs[g]=m1+m2;
    }
    int g1=0; for(int g=1;g<4;g++) if(gs[g]>gs[g1]) g1=g;
    int g2=-1; for(int g=0;g<4;g++){ if(g==g1) continue; if(g2<0||gs[g]>gs[g2]) g2=g; }
    bool taken[16];
    #pragma unroll
    for(int i=0;i<16;i++) taken[i]=false;
    int idx[4];
    for(int j=0;j<4;j++){
      int best=-1; float bv=-1e30f;
      for(int i=0;i<16;i++){
        int g=i>>2;
        if(g!=g1 && g!=g2) continue;
        if(taken[i]) continue;
        if(best<0 || sfc[i]>bv){ best=i; bv=sfc[i]; }
      }
      taken[best]=true; idx[j]=best;
    }
    float w[4]; float s=0.f;
    #pragma unroll
    for(int j=0;j<4;j++){ w[j]=sS[idx[j]]; s+=w[j]; }
    s += 1e-20f;
    #pragma unroll
    for(int j=0;j<4;j++){
      topk_idx[t*4+j]=idx[j];
      topk_w[t*4+j]=w[j]/s;
      atomicAdd(&counts[idx[j]],1);
    }
  }
}

__global__ void k_zero(int* __restrict__ counts){ if(threadIdx.x<16) counts[threadIdx.x]=0; }

__global__ void k_scan(const int* __restrict__ counts, int* __restrict__ offs, int* __restrict__ cursor){
  if(threadIdx.x==0){
    int s=0;
    for(int e2=0;e2<16;e2++){ offs[e2]=s; cursor[e2]=s; s+=counts[e2]; }
    offs[16]=s;
  }
}

__global__ __launch_bounds__(256) void k_scatter(const int* __restrict__ topk_idx,
    int* __restrict__ cursor, int* __restrict__ pair_tok, int* __restrict__ tok2pair){
  int i = blockIdx.x*256 + threadIdx.x;  // 0..8191
  int e = topk_idx[i];
  int pos = atomicAdd(&cursor[e],1);
  pair_tok[pos] = i>>2;
  tok2pair[i] = pos;
}

// ---- K15: out0 = sum_j 2*w_j*y[pair_j] + shared ----
__global__ __launch_bounds__(256) void k_combine(const float* __restrict__ y,
    const float* __restrict__ sout, const int* __restrict__ tok2pair,
    const float* __restrict__ topk_w, float* __restrict__ out0){
  int t = blockIdx.x, tid = threadIdx.x;
  int p[4]; float w[4];
  #pragma unroll
  for(int j=0;j<4;j++){ p[j]=tok2pair[t*4+j]; w[j]=topk_w[t*4+j]*2.0f; }
  const long base = (long)t*H_DIM;
  #pragma unroll
  for(int i=0;i<4;i++){
    int c = tid + i*256;
    float v = sout[base+c];
    #pragma unroll
    for(int j=0;j<4;j++) v += w[j]*y[(long long)p[j]*H_DIM + c];
    out0[base+c] = v;
  }
}

extern "C" void kernel_launch(void* const* d_in, const int* in_sizes, int n_in,
                              void* d_out, int out_size, void* d_ws, size_t ws_size,
                              hipStream_t stream) {
  const float* hs   = (const float*)d_in[0];
  const float* rsd  = (const float*)d_in[1];
  const int*   pos  = (const int*)d_in[2];
  const float* ln1  = (const float*)d_in[3];
  const float* qkvw = (const float*)d_in[4];
  const float* qnw  = (const float*)d_in[5];
  const float* knw  = (const float*)d_in[6];
  const float* dw   = (const float*)d_in[7];
  const float* ln2  = (const float*)d_in[8];
  const float* gw   = (const float*)d_in[9];
  const float* eb   = (const float*)d_in[10];
  const float* w13  = (const float*)d_in[11];
  const float* w2   = (const float*)d_in[12];
  const float* wsgu = (const float*)d_in[13];
  const float* wsd  = (const float*)d_in[14];
  float* out0 = (float*)d_out;                      // mlp_out  [T,H]
  float* out1 = out0 + (size_t)T_TOK*H_DIM;         // resid2   [T,H]

  float* W = (float*)d_ws;
  const size_t TH = (size_t)T_TOK*H_DIM;            // 2097152 floats (8 MB)
  // Phase-checked aliasing (TH units):
  //  [0,1)    resid      live A..E          | reused: ybuf [0,4) J..K
  //  [1,2)    h A..B  -> ctx D..E -> h2 F..I
  //  [2,3.5)  qkv B..C;  r2 [2,3) E..F;  sact [2,3) H
  //  [3.5,5)  qb/kb/vb C..D
  //  [4.5,8.5) act I..J
  //  [8.5,9.5) sout H..K
  //  [9.5,..) small index/weight arrays
  float* resid  = W;
  float* h      = W + TH;
  float* ctx    = W + TH;
  float* h2     = W + TH;
  float* qkv    = W + 2*TH;                         // 1.5TH
  float* r2     = W + 2*TH;
  float* sact   = W + 2*TH;
  float* qb     = W + (TH*7)/2;                     // 3.5TH: qb TH? no: qb is NH*T*HD = TH
  float* kb     = qb + TH;                          // 0.25TH
  float* vb     = kb + (size_t)NKVH*T_TOK*HDIM;     // 0.25TH -> ends at 5TH... see note
  float* act    = W + (TH*9)/2;                     // [4.5, 8.5)
  float* sout   = W + (TH*17)/2;                    // [8.5, 9.5)
  float* ybuf   = W;                                // [0,4) live J..K
  float* topkw  = W + (TH*19)/2;                    // 8192 floats
  int*   topki  = (int*)(topkw + NPAIR);
  int*   ptok   = topki + NPAIR;
  int*   t2p    = ptok + NPAIR;
  int*   cnt    = t2p + NPAIR;
  int*   offs   = cnt + 16;
  int*   cur    = offs + 17;
  // NOTE: qb spans [3.5,4.5), kb [4.5,4.75), vb [4.75,5.0) — kb/vb overlap act's
  // region but act is only written in phase I, after attention (D) consumed kb/vb.

  // A. resid + rmsnorm
  k_add_rmsnorm<<<T_TOK, 256, 0, stream>>>(hs, rsd, ln1, resid, h);
  // B. qkv = h @ qkv_w  [2048x1024 @ 1024x1536]
  gemm_f32<false,false,0><<<dim3(QKV_DIM/64, T_TOK/128, 1), 256, 0, stream>>>(
      h, H_DIM, qkvw, QKV_DIM, 0, qkv, QKV_DIM, nullptr, nullptr, nullptr, T_TOK, H_DIM);
  // C. q/k norm + rope, v copy
  k_qkv_post<<<dim3(12, T_TOK), 64, 0, stream>>>(qkv, qnw, knw, pos, qb, kb, vb);
  // D. attention
  k_attn<<<dim3(NHEAD, T_TOK), 256, 0, stream>>>(qb, kb, vb, ctx);
  // E. resid2 = ctx @ dense_w + resid
  gemm_f32<false,false,1><<<dim3(H_DIM/64, T_TOK/128, 1), 256, 0, stream>>>(
      ctx, NHEAD*HDIM, dw, H_DIM, 0, r2, H_DIM, resid, nullptr, nullptr, T_TOK, NHEAD*HDIM);
  // F. h2 = rmsnorm(resid2); write resid2 -> out1
  k_rms2<<<T_TOK, 256, 0, stream>>>(r2, ln2, h2, out1);
  // G. router
  k_zero<<<1, 64, 0, stream>>>(cnt);
  k_router<<<T_TOK, 256, 0, stream>>>(h2, gw, eb, topki, topkw, cnt);
  k_scan<<<1, 64, 0, stream>>>(cnt, offs, cur);
  k_scatter<<<NPAIR/256, 256, 0, stream>>>(topki, cur, ptok, t2p);
  // H. shared expert (before MoE so h2's last reader is the MoE gateup)
  gemm_gateup<false,false><<<dim3(FS_DIM/64, T_TOK/128, 1), 256, 0, stream>>>(
      h2, H_DIM, wsgu, 2*FS_DIM, 0, FS_DIM, sact, FS_DIM, nullptr, nullptr, T_TOK, H_DIM);
  gemm_f32<false,false,0><<<dim3(H_DIM/64, T_TOK/128, 1), 256, 0, stream>>>(
      sact, FS_DIM, wsd, H_DIM, 0, sout, H_DIM, nullptr, nullptr, nullptr, T_TOK, FS_DIM);
  // I. MoE gateup (grouped+gathered); grid.y=64 covers worst-case 8192 rows/expert
  gemm_gateup<true,true><<<dim3(F_DIM/64, 64, E_EXP), 256, 0, stream>>>(
      h2, H_DIM, w13, 2*F_DIM, (long long)H_DIM*2*F_DIM, F_DIM,
      act, F_DIM, ptok, offs, 0, H_DIM);
  // J. MoE down (grouped): ybuf[pair] = act[pair] @ w2[e]
  gemm_f32<true,false,0><<<dim3(H_DIM/64, 64, E_EXP), 256, 0, stream>>>(
      act, F_DIM, w2, H_DIM, (long long)F_DIM*H_DIM, ybuf, H_DIM,
      nullptr, nullptr, offs, 0, F_DIM);
  // K. combine -> out0
  k_combine<<<T_TOK, 256, 0, stream>>>(ybuf, sout, t2p, topkw, out0);
}

// Round 3
// 1912.787 us; speedup vs baseline: 1.9000x; 1.9000x over previous
//
#include <hip/hip_runtime.h>
#include <hip/hip_bf16.h>

// BailingMoeBlock: T=2048 H=1024 NH=8 NKV=2 HD=128 E=16 TOPK=4 NG=4 TKG=2 F=FS=1024
// Round 3: flash-style tiled attention (online softmax, BQ=32/BK=64, paired
// complementary q-tiles -> 256 perfectly-balanced blocks). Rest unchanged fp32.

#define T_TOK 2048
#define H_DIM 1024
#define NHEAD 8
#define NKVH 2
#define HDIM 128
#define QKV_DIM 1536
#define E_EXP 16
#define TOPKE 4
#define F_DIM 1024
#define FS_DIM 1024
#define NPAIR (T_TOK*TOPKE)
#define EPS_F 1e-6f

#define DEV __device__ __forceinline__

// ---- block reductions (256 threads = 4 waves) ----
DEV float bred_sum(float v, float* sm){
  #pragma unroll
  for(int o=32;o>0;o>>=1) v += __shfl_down(v,o);
  int w = threadIdx.x>>6, l = threadIdx.x&63;
  __syncthreads();
  if(l==0) sm[w]=v;
  __syncthreads();
  return sm[0]+sm[1]+sm[2]+sm[3];
}

// ---- K1: resid = hs + residual ; h = rmsnorm(resid, ln1_w) ----
__global__ __launch_bounds__(256) void k_add_rmsnorm(const float* __restrict__ hs,
    const float* __restrict__ rs, const float* __restrict__ w,
    float* __restrict__ resid, float* __restrict__ h){
  int t = blockIdx.x, tid = threadIdx.x;
  __shared__ float sm[4];
  const long base = (long)t*H_DIM;
  float x[4]; float ss = 0.f;
  #pragma unroll
  for(int i=0;i<4;i++){
    int c = tid + i*256;
    float v = hs[base+c] + rs[base+c];
    x[i]=v; resid[base+c]=v; ss += v*v;
  }
  float tot = bred_sum(ss, sm);
  float rms = rsqrtf(tot/(float)H_DIM + EPS_F);
  #pragma unroll
  for(int i=0;i<4;i++){
    int c = tid + i*256;
    h[base+c] = x[i]*rms*w[c];
  }
}

// ---- generic fp32 GEMM: C[MxN] = A[MxK] * B[KxN] (+D) ----
template<bool GROUPED, bool GATHER, int EPI_ADD>
__global__ __launch_bounds__(256) void gemm_f32(
    const float* __restrict__ A, int lda,
    const float* __restrict__ B, int ldb, long long bstride,
    float* __restrict__ C, int ldc,
    const float* __restrict__ D,
    const int* __restrict__ rowidx, const int* __restrict__ grpoff,
    int Mdense, int K){
  const int z = blockIdx.z;
  const int row_begin = GROUPED ? grpoff[z]   : 0;
  const int row_end   = GROUPED ? grpoff[z+1] : Mdense;
  const int m0 = row_begin + blockIdx.y*128;
  if(m0 >= row_end) return;
  const int n0 = blockIdx.x*64;
  const float* Bz = B + (long long)z*bstride;

  __shared__ float As[16][132];
  __shared__ float Bs[16][65];
  float acc[8][4];
  #pragma unroll
  for(int i=0;i<8;i++)
    #pragma unroll
    for(int j=0;j<4;j++) acc[i][j]=0.f;

  const int tid = threadIdx.x;
  const int tx = tid & 15, ty = tid >> 4;
  const int ar = tid >> 1, ac = (tid & 1)*8;
  const int brr = tid >> 4, bc = (tid & 15)*4;

  const int arow_g = m0 + ar;
  const bool avalid = arow_g < row_end;
  const int arow = avalid ? (GATHER ? rowidx[arow_g] : arow_g) : 0;
  const float* Aptr = A + (long long)arow*lda;

  for(int k0=0;k0<K;k0+=16){
    float4 a0 = make_float4(0,0,0,0), a1 = a0;
    if(avalid){
      a0 = *(const float4*)(Aptr + k0 + ac);
      a1 = *(const float4*)(Aptr + k0 + ac + 4);
    }
    float4 bv = *(const float4*)(Bz + (long long)(k0+brr)*ldb + n0 + bc);
    __syncthreads();
    As[ac+0][ar]=a0.x; As[ac+1][ar]=a0.y; As[ac+2][ar]=a0.z; As[ac+3][ar]=a0.w;
    As[ac+4][ar]=a1.x; As[ac+5][ar]=a1.y; As[ac+6][ar]=a1.z; As[ac+7][ar]=a1.w;
    Bs[brr][bc+0]=bv.x; Bs[brr][bc+1]=bv.y; Bs[brr][bc+2]=bv.z; Bs[brr][bc+3]=bv.w;
    __syncthreads();
    #pragma unroll
    for(int kk=0;kk<16;kk++){
      float a[8], b[4];
      #pragma unroll
      for(int i=0;i<8;i++) a[i]=As[kk][ty*8+i];
      #pragma unroll
      for(int j=0;j<4;j++) b[j]=Bs[kk][tx*4+j];
      #pragma unroll
      for(int i=0;i<8;i++)
        #pragma unroll
        for(int j=0;j<4;j++) acc[i][j] = fmaf(a[i], b[j], acc[i][j]);
    }
  }
  #pragma unroll
  for(int i=0;i<8;i++){
    int r = m0 + ty*8 + i;
    if(r < row_end){
      float* crow = C + (long long)r*ldc + n0 + tx*4;
      float4 v = make_float4(acc[i][0],acc[i][1],acc[i][2],acc[i][3]);
      if(EPI_ADD){
        const float4 d = *(const float4*)(D + (long long)r*ldc + n0 + tx*4);
        v.x+=d.x; v.y+=d.y; v.z+=d.z; v.w+=d.w;
      }
      *(float4*)crow = v;
    }
  }
}

// ---- gate_up GEMM with fused SiLU*up epilogue ----
template<bool GROUPED, bool GATHER>
__global__ __launch_bounds__(256) void gemm_gateup(
    const float* __restrict__ A, int lda,
    const float* __restrict__ B, int ldb, long long bstride, int uoff,
    float* __restrict__ Cact, int ldc,
    const int* __restrict__ rowidx, const int* __restrict__ grpoff,
    int Mdense, int K){
  const int z = blockIdx.z;
  const int row_begin = GROUPED ? grpoff[z]   : 0;
  const int row_end   = GROUPED ? grpoff[z+1] : Mdense;
  const int m0 = row_begin + blockIdx.y*128;
  if(m0 >= row_end) return;
  const int n0 = blockIdx.x*64;
  const float* Bz = B + (long long)z*bstride;

  __shared__ float As[16][132];
  __shared__ float Bg[16][65];
  __shared__ float Bu[16][65];
  float accg[8][4], accu[8][4];
  #pragma unroll
  for(int i=0;i<8;i++)
    #pragma unroll
    for(int j=0;j<4;j++){ accg[i][j]=0.f; accu[i][j]=0.f; }

  const int tid = threadIdx.x;
  const int tx = tid & 15, ty = tid >> 4;
  const int ar = tid >> 1, ac = (tid & 1)*8;
  const int brr = tid >> 4, bc = (tid & 15)*4;

  const int arow_g = m0 + ar;
  const bool avalid = arow_g < row_end;
  const int arow = avalid ? (GATHER ? rowidx[arow_g] : arow_g) : 0;
  const float* Aptr = A + (long long)arow*lda;

  for(int k0=0;k0<K;k0+=16){
    float4 a0 = make_float4(0,0,0,0), a1 = a0;
    if(avalid){
      a0 = *(const float4*)(Aptr + k0 + ac);
      a1 = *(const float4*)(Aptr + k0 + ac + 4);
    }
    const float* bp = Bz + (long long)(k0+brr)*ldb + n0 + bc;
    float4 bg4 = *(const float4*)(bp);
    float4 bu4 = *(const float4*)(bp + uoff);
    __syncthreads();
    As[ac+0][ar]=a0.x; As[ac+1][ar]=a0.y; As[ac+2][ar]=a0.z; As[ac+3][ar]=a0.w;
    As[ac+4][ar]=a1.x; As[ac+5][ar]=a1.y; As[ac+6][ar]=a1.z; As[ac+7][ar]=a1.w;
    Bg[brr][bc+0]=bg4.x; Bg[brr][bc+1]=bg4.y; Bg[brr][bc+2]=bg4.z; Bg[brr][bc+3]=bg4.w;
    Bu[brr][bc+0]=bu4.x; Bu[brr][bc+1]=bu4.y; Bu[brr][bc+2]=bu4.z; Bu[brr][bc+3]=bu4.w;
    __syncthreads();
    #pragma unroll
    for(int kk=0;kk<16;kk++){
      float a[8], bg[4], bu2[4];
      #pragma unroll
      for(int i=0;i<8;i++) a[i]=As[kk][ty*8+i];
      #pragma unroll
      for(int j=0;j<4;j++){ bg[j]=Bg[kk][tx*4+j]; bu2[j]=Bu[kk][tx*4+j]; }
      #pragma unroll
      for(int i=0;i<8;i++)
        #pragma unroll
        for(int j=0;j<4;j++){
          accg[i][j] = fmaf(a[i], bg[j],  accg[i][j]);
          accu[i][j] = fmaf(a[i], bu2[j], accu[i][j]);
        }
    }
  }
  #pragma unroll
  for(int i=0;i<8;i++){
    int r = m0 + ty*8 + i;
    if(r < row_end){
      float* crow = Cact + (long long)r*ldc + n0 + tx*4;
      float4 v;
      float g0=accg[i][0], g1=accg[i][1], g2=accg[i][2], g3=accg[i][3];
      v.x = (g0/(1.f+__expf(-g0)))*accu[i][0];
      v.y = (g1/(1.f+__expf(-g1)))*accu[i][1];
      v.z = (g2/(1.f+__expf(-g2)))*accu[i][2];
      v.w = (g3/(1.f+__expf(-g3)))*accu[i][3];
      *(float4*)crow = v;
    }
  }
}

// ---- K3: per-(t,slot) q/k rmsnorm + rope, v copy. 64 threads. ----
__global__ __launch_bounds__(64) void k_qkv_post(const float* __restrict__ qkv,
    const float* __restrict__ qw, const float* __restrict__ kw,
    const int* __restrict__ pos,
    float* __restrict__ qb, float* __restrict__ kb, float* __restrict__ vb){
  int slot = blockIdx.x, t = blockIdx.y, lane = threadIdx.x;
  const float* x = qkv + (long long)t*QKV_DIM + slot*HDIM;
  float x0 = x[lane], x1 = x[lane+64];
  if(slot < 10){
    float ss = x0*x0 + x1*x1;
    #pragma unroll
    for(int o=32;o>0;o>>=1) ss += __shfl_xor(ss,o);
    float rms = rsqrtf(ss/(float)HDIM + EPS_F);
    const float* w = (slot<8)? qw : kw;
    float n0 = x0*rms*w[lane];
    float n1 = x1*rms*w[lane+64];
    float p = (float)pos[t];
    float invf = __expf(-((float)lane/64.f)*9.210340371976184f);
    float ang = p*invf;
    float s = sinf(ang), c = cosf(ang);
    float o0 = n0*c - n1*s;
    float o1 = n1*c + n0*s;
    float* dst = (slot<8)? (qb + ((long long)slot*T_TOK + t)*HDIM)
                         : (kb + ((long long)(slot-8)*T_TOK + t)*HDIM);
    dst[lane]=o0; dst[lane+64]=o1;
  } else {
    float* dst = vb + ((long long)(slot-10)*T_TOK + t)*HDIM;
    dst[lane]=x0; dst[lane+64]=x1;
  }
}

// ---- K4: flash attention. Block = (head, q-tile pair). 256 threads.
// BQ=32 queries, BK=64 keys/tile. Pair (i, 63-i) => uniform 33 k-tiles/block.
#define BQ 32
#define BK 64
__global__ __launch_bounds__(256) void k_flash(const float* __restrict__ qb,
    const float* __restrict__ kb, const float* __restrict__ vb,
    float* __restrict__ ctx){
  const int h = blockIdx.x, pair = blockIdx.y;
  const int kv = h >> 2;
  const int tid = threadIdx.x;
  const int tx = tid & 15, ty = tid >> 4;
  __shared__ float Qs[HDIM][34];   // transposed, even pad (aligned float2)
  __shared__ float Ks[HDIM][68];   // transposed, pad 68 (aligned float4)
  __shared__ float Vs[BK][HDIM];   // natural
  __shared__ float Ps[BK][34];     // P round-trip
  const float scale = 0.08838834764831845f;

  for(int which=0; which<2; which++){
    const int qt = which ? (63 - pair) : pair;
    const int q0 = qt * BQ;
    // stage Q tile (transposed)
    {
      int r = tid >> 3, cb = (tid & 7) * 16;
      const float* src = qb + ((long long)h*T_TOK + q0 + r)*HDIM + cb;
      #pragma unroll
      for(int j4=0;j4<4;j4++){
        float4 v4 = *(const float4*)(src + j4*4);
        Qs[cb+j4*4+0][r]=v4.x; Qs[cb+j4*4+1][r]=v4.y;
        Qs[cb+j4*4+2][r]=v4.z; Qs[cb+j4*4+3][r]=v4.w;
      }
    }
    float m0=-1e30f, m1=-1e30f, l0=0.f, l1=0.f;
    float O0[8], O1[8];
    #pragma unroll
    for(int j=0;j<8;j++){ O0[j]=0.f; O1[j]=0.f; }
    const int nkt = (qt>>1) + 1;
    for(int kt=0; kt<nkt; kt++){
      const int k0 = kt*BK;
      __syncthreads();           // prev iter's LDS readers done
      {
        int r = tid >> 2, cb = (tid & 3) * 32;
        const float* ks = kb + ((long long)kv*T_TOK + k0 + r)*HDIM + cb;
        const float* vs = vb + ((long long)kv*T_TOK + k0 + r)*HDIM + cb;
        #pragma unroll
        for(int j4=0;j4<8;j4++){
          float4 v4 = *(const float4*)(ks + j4*4);
          Ks[cb+j4*4+0][r]=v4.x; Ks[cb+j4*4+1][r]=v4.y;
          Ks[cb+j4*4+2][r]=v4.z; Ks[cb+j4*4+3][r]=v4.w;
          *(float4*)(&Vs[r][cb+j4*4]) = *(const float4*)(vs + j4*4);
        }
      }
      __syncthreads();
      // S tile: thread computes 2q x 4k
      float s00=0,s01=0,s02=0,s03=0,s10=0,s11=0,s12=0,s13=0;
      const float* qsp = &Qs[0][ty*2];
      const float* ksp = &Ks[0][tx*4];
      #pragma unroll 4
      for(int kk=0;kk<HDIM;kk++){
        float2 q2 = *(const float2*)(qsp + kk*34);
        float4 k4 = *(const float4*)(ksp + kk*68);
        s00=fmaf(q2.x,k4.x,s00); s01=fmaf(q2.x,k4.y,s01);
        s02=fmaf(q2.x,k4.z,s02); s03=fmaf(q2.x,k4.w,s03);
        s10=fmaf(q2.y,k4.x,s10); s11=fmaf(q2.y,k4.y,s11);
        s12=fmaf(q2.y,k4.z,s12); s13=fmaf(q2.y,k4.w,s13);
      }
      float s[2][4] = {{s00*scale,s01*scale,s02*scale,s03*scale},
                       {s10*scale,s11*scale,s12*scale,s13*scale}};
      if(kt == nkt-1){
        #pragma unroll
        for(int qi=0;qi<2;qi++)
          #pragma unroll
          for(int ki=0;ki<4;ki++)
            if(k0 + tx*4 + ki > q0 + ty*2 + qi) s[qi][ki] = -1e30f;
      }
      // online softmax (row groups = 16 contiguous lanes)
      float rm0 = fmaxf(fmaxf(s[0][0],s[0][1]),fmaxf(s[0][2],s[0][3]));
      float rm1 = fmaxf(fmaxf(s[1][0],s[1][1]),fmaxf(s[1][2],s[1][3]));
      #pragma unroll
      for(int o=1;o<16;o<<=1){
        rm0 = fmaxf(rm0, __shfl_xor(rm0,o));
        rm1 = fmaxf(rm1, __shfl_xor(rm1,o));
      }
      float mn0 = fmaxf(m0, rm0), mn1 = fmaxf(m1, rm1);
      float a0 = __expf(m0-mn0), a1 = __expf(m1-mn1);
      float p[2][4]; float rs0=0.f, rs1=0.f;
      #pragma unroll
      for(int ki=0;ki<4;ki++){
        p[0][ki] = __expf(s[0][ki]-mn0); rs0 += p[0][ki];
        p[1][ki] = __expf(s[1][ki]-mn1); rs1 += p[1][ki];
      }
      #pragma unroll
      for(int o=1;o<16;o<<=1){
        rs0 += __shfl_xor(rs0,o);
        rs1 += __shfl_xor(rs1,o);
      }
      l0 = l0*a0 + rs0; l1 = l1*a1 + rs1;
      m0 = mn0; m1 = mn1;
      #pragma unroll
      for(int j=0;j<8;j++){ O0[j]*=a0; O1[j]*=a1; }
      // P -> LDS (safe: no Ps reader since top-of-loop barrier)
      #pragma unroll
      for(int ki=0;ki<4;ki++){
        Ps[tx*4+ki][ty*2+0] = p[0][ki];
        Ps[tx*4+ki][ty*2+1] = p[1][ki];
      }
      __syncthreads();
      // PV: thread accumulates 2q x 8d
      const float* vsp = &Vs[0][tx*8];
      const float* psp = &Ps[0][ty*2];
      #pragma unroll 2
      for(int k=0;k<BK;k++){
        float2 pf = *(const float2*)(psp + k*34);
        float4 va = *(const float4*)(vsp + k*HDIM);
        float4 vb4 = *(const float4*)(vsp + k*HDIM + 4);
        O0[0]=fmaf(pf.x,va.x,O0[0]); O0[1]=fmaf(pf.x,va.y,O0[1]);
        O0[2]=fmaf(pf.x,va.z,O0[2]); O0[3]=fmaf(pf.x,va.w,O0[3]);
        O0[4]=fmaf(pf.x,vb4.x,O0[4]); O0[5]=fmaf(pf.x,vb4.y,O0[5]);
        O0[6]=fmaf(pf.x,vb4.z,O0[6]); O0[7]=fmaf(pf.x,vb4.w,O0[7]);
        O1[0]=fmaf(pf.y,va.x,O1[0]); O1[1]=fmaf(pf.y,va.y,O1[1]);
        O1[2]=fmaf(pf.y,va.z,O1[2]); O1[3]=fmaf(pf.y,va.w,O1[3]);
        O1[4]=fmaf(pf.y,vb4.x,O1[4]); O1[5]=fmaf(pf.y,vb4.y,O1[5]);
        O1[6]=fmaf(pf.y,vb4.z,O1[6]); O1[7]=fmaf(pf.y,vb4.w,O1[7]);
      }
    }
    // epilogue: ctx[t][h*128+d] = O/l
    float inv0 = 1.f/l0, inv1 = 1.f/l1;
    float* dst0 = ctx + ((long long)(q0+ty*2))*(NHEAD*HDIM) + h*HDIM + tx*8;
    float* dst1 = dst0 + NHEAD*HDIM;
    float4 o;
    o = make_float4(O0[0]*inv0,O0[1]*inv0,O0[2]*inv0,O0[3]*inv0); *(float4*)dst0 = o;
    o = make_float4(O0[4]*inv0,O0[5]*inv0,O0[6]*inv0,O0[7]*inv0); *(float4*)(dst0+4) = o;
    o = make_float4(O1[0]*inv1,O1[1]*inv1,O1[2]*inv1,O1[3]*inv1); *(float4*)dst1 = o;
    o = make_float4(O1[4]*inv1,O1[5]*inv1,O1[6]*inv1,O1[7]*inv1); *(float4*)(dst1+4) = o;
  }
}

// ---- K6: h2 = rmsnorm(resid2, ln2_w); also write resid2 to out[1] ----
__global__ __launch_bounds__(256) void k_rms2(const float* __restrict__ r2,
    const float* __restrict__ w, float* __restrict__ h2, float* __restrict__ out2){
  int t = blockIdx.x, tid = threadIdx.x;
  __shared__ float sm[4];
  const long base = (long)t*H_DIM;
  float x[4]; float ss=0.f;
  #pragma unroll
  for(int i=0;i<4;i++){
    int c = tid+i*256;
    float v = r2[base+c];
    x[i]=v; ss += v*v;
    out2[base+c] = v;
  }
  float tot = bred_sum(ss, sm);
  float rms = rsqrtf(tot/(float)H_DIM + EPS_F);
  #pragma unroll
  for(int i=0;i<4;i++){
    int c = tid+i*256;
    h2[base+c] = x[i]*rms*w[c];
  }
}

// ---- K7: router ----
__global__ __launch_bounds__(256) void k_router(const float* __restrict__ h2,
    const float* __restrict__ gw, const float* __restrict__ eb,
    int* __restrict__ topk_idx, float* __restrict__ topk_w, int* __restrict__ counts){
  int t = blockIdx.x, tid = threadIdx.x;
  int e = tid & 15, seg = tid >> 4;
  const float* hrow = h2 + (long long)t*H_DIM;
  float part = 0.f;
  #pragma unroll 4
  for(int i=0;i<64;i++){
    int hh = seg*64 + i;
    part += hrow[hh]*gw[hh*E_EXP + e];
  }
  __shared__ float pm[16][17];
  __shared__ float sS[16], sfc[16];
  pm[seg][e] = part;
  __syncthreads();
  if(tid < 16){
    float l = 0.f;
    #pragma unroll
    for(int s=0;s<16;s++) l += pm[s][tid];
    float sg = 1.f/(1.f+expf(-l));
    sS[tid]=sg; sfc[tid]=sg+eb[tid];
  }
  __syncthreads();
  if(tid==0){
    float gs[4];
    #pragma unroll
    for(int g=0; g<4; g++){
      float m1=-1e30f, m2=-1e30f;
      for(int j=0;j<4;j++){
        float v=sfc[g*4+j];
        if(v>m1){ m2=m1; m1=v; } else if(v>m2){ m2=v; }
      }
      gs[g]=m1+m2;
    }
    int g1=0; for(int g=1;g<4;g++) if(gs[g]>gs[g1]) g1=g;
    int g2=-1; for(int g=0;g<4;g++){ if(g==g1) continue; if(g2<0||gs[g]>gs[g2]) g2=g; }
    bool taken[16];
    #pragma unroll
    for(int i=0;i<16;i++) taken[i]=false;
    int idx[4];
    for(int j=0;j<4;j++){
      int best=-1; float bv=-1e30f;
      for(int i=0;i<16;i++){
        int g=i>>2;
        if(g!=g1 && g!=g2) continue;
        if(taken[i]) continue;
        if(best<0 || sfc[i]>bv){ best=i; bv=sfc[i]; }
      }
      taken[best]=true; idx[j]=best;
    }
    float w[4]; float s=0.f;
    #pragma unroll
    for(int j=0;j<4;j++){ w[j]=sS[idx[j]]; s+=w[j]; }
    s += 1e-20f;
    #pragma unroll
    for(int j=0;j<4;j++){
      topk_idx[t*4+j]=idx[j];
      topk_w[t*4+j]=w[j]/s;
      atomicAdd(&counts[idx[j]],1);
    }
  }
}

__global__ void k_zero(int* __restrict__ counts){ if(threadIdx.x<16) counts[threadIdx.x]=0; }

__global__ void k_scan(const int* __restrict__ counts, int* __restrict__ offs, int* __restrict__ cursor){
  if(threadIdx.x==0){
    int s=0;
    for(int e2=0;e2<16;e2++){ offs[e2]=s; cursor[e2]=s; s+=counts[e2]; }
    offs[16]=s;
  }
}

__global__ __launch_bounds__(256) void k_scatter(const int* __restrict__ topk_idx,
    int* __restrict__ cursor, int* __restrict__ pair_tok, int* __restrict__ tok2pair){
  int i = blockIdx.x*256 + threadIdx.x;
  int e = topk_idx[i];
  int pos = atomicAdd(&cursor[e],1);
  pair_tok[pos] = i>>2;
  tok2pair[i] = pos;
}

// ---- K15: out0 = sum_j 2*w_j*y[pair_j] + shared ----
__global__ __launch_bounds__(256) void k_combine(const float* __restrict__ y,
    const float* __restrict__ sout, const int* __restrict__ tok2pair,
    const float* __restrict__ topk_w, float* __restrict__ out0){
  int t = blockIdx.x, tid = threadIdx.x;
  int p[4]; float w[4];
  #pragma unroll
  for(int j=0;j<4;j++){ p[j]=tok2pair[t*4+j]; w[j]=topk_w[t*4+j]*2.0f; }
  const long base = (long)t*H_DIM;
  #pragma unroll
  for(int i=0;i<4;i++){
    int c = tid + i*256;
    float v = sout[base+c];
    #pragma unroll
    for(int j=0;j<4;j++) v += w[j]*y[(long long)p[j]*H_DIM + c];
    out0[base+c] = v;
  }
}

extern "C" void kernel_launch(void* const* d_in, const int* in_sizes, int n_in,
                              void* d_out, int out_size, void* d_ws, size_t ws_size,
                              hipStream_t stream) {
  const float* hs   = (const float*)d_in[0];
  const float* rsd  = (const float*)d_in[1];
  const int*   pos  = (const int*)d_in[2];
  const float* ln1  = (const float*)d_in[3];
  const float* qkvw = (const float*)d_in[4];
  const float* qnw  = (const float*)d_in[5];
  const float* knw  = (const float*)d_in[6];
  const float* dw   = (const float*)d_in[7];
  const float* ln2  = (const float*)d_in[8];
  const float* gw   = (const float*)d_in[9];
  const float* eb   = (const float*)d_in[10];
  const float* w13  = (const float*)d_in[11];
  const float* w2   = (const float*)d_in[12];
  const float* wsgu = (const float*)d_in[13];
  const float* wsd  = (const float*)d_in[14];
  float* out0 = (float*)d_out;
  float* out1 = out0 + (size_t)T_TOK*H_DIM;

  float* W = (float*)d_ws;
  const size_t TH = (size_t)T_TOK*H_DIM;
  float* resid  = W;
  float* h      = W + TH;
  float* ctx    = W + TH;
  float* h2     = W + TH;
  float* qkv    = W + 2*TH;
  float* r2     = W + 2*TH;
  float* sact   = W + 2*TH;
  float* qb     = W + (TH*7)/2;
  float* kb     = qb + TH;
  float* vb     = kb + (size_t)NKVH*T_TOK*HDIM;
  float* act    = W + (TH*9)/2;
  float* sout   = W + (TH*17)/2;
  float* ybuf   = W;
  float* topkw  = W + (TH*19)/2;
  int*   topki  = (int*)(topkw + NPAIR);
  int*   ptok   = topki + NPAIR;
  int*   t2p    = ptok + NPAIR;
  int*   cnt    = t2p + NPAIR;
  int*   offs   = cnt + 16;
  int*   cur    = offs + 17;

  // A. resid + rmsnorm
  k_add_rmsnorm<<<T_TOK, 256, 0, stream>>>(hs, rsd, ln1, resid, h);
  // B. qkv = h @ qkv_w
  gemm_f32<false,false,0><<<dim3(QKV_DIM/64, T_TOK/128, 1), 256, 0, stream>>>(
      h, H_DIM, qkvw, QKV_DIM, 0, qkv, QKV_DIM, nullptr, nullptr, nullptr, T_TOK, H_DIM);
  // C. q/k norm + rope
  k_qkv_post<<<dim3(12, T_TOK), 64, 0, stream>>>(qkv, qnw, knw, pos, qb, kb, vb);
  // D. flash attention (8 heads x 32 complementary pairs = 256 uniform blocks)
  k_flash<<<dim3(NHEAD, T_TOK/BQ/2), 256, 0, stream>>>(qb, kb, vb, ctx);
  // E. resid2 = ctx @ dense_w + resid
  gemm_f32<false,false,1><<<dim3(H_DIM/64, T_TOK/128, 1), 256, 0, stream>>>(
      ctx, NHEAD*HDIM, dw, H_DIM, 0, r2, H_DIM, resid, nullptr, nullptr, T_TOK, NHEAD*HDIM);
  // F. h2 = rmsnorm(resid2); resid2 -> out1
  k_rms2<<<T_TOK, 256, 0, stream>>>(r2, ln2, h2, out1);
  // G. router
  k_zero<<<1, 64, 0, stream>>>(cnt);
  k_router<<<T_TOK, 256, 0, stream>>>(h2, gw, eb, topki, topkw, cnt);
  k_scan<<<1, 64, 0, stream>>>(cnt, offs, cur);
  k_scatter<<<NPAIR/256, 256, 0, stream>>>(topki, cur, ptok, t2p);
  // H. shared expert
  gemm_gateup<false,false><<<dim3(FS_DIM/64, T_TOK/128, 1), 256, 0, stream>>>(
      h2, H_DIM, wsgu, 2*FS_DIM, 0, FS_DIM, sact, FS_DIM, nullptr, nullptr, T_TOK, H_DIM);
  gemm_f32<false,false,0><<<dim3(H_DIM/64, T_TOK/128, 1), 256, 0, stream>>>(
      sact, FS_DIM, wsd, H_DIM, 0, sout, H_DIM, nullptr, nullptr, nullptr, T_TOK, FS_DIM);
  // I. MoE gateup (grouped+gathered)
  gemm_gateup<true,true><<<dim3(F_DIM/64, 64, E_EXP), 256, 0, stream>>>(
      h2, H_DIM, w13, 2*F_DIM, (long long)H_DIM*2*F_DIM, F_DIM,
      act, F_DIM, ptok, offs, 0, H_DIM);
  // J. MoE down (grouped)
  gemm_f32<true,false,0><<<dim3(H_DIM/64, 64, E_EXP), 256, 0, stream>>>(
      act, F_DIM, w2, H_DIM, (long long)F_DIM*H_DIM, ybuf, H_DIM,
      nullptr, nullptr, offs, 0, F_DIM);
  // K. combine
  k_combine<<<T_TOK, 256, 0, stream>>>(ybuf, sout, t2p, topkw, out0);
}

// Round 4
// 1162.812 us; speedup vs baseline: 3.1254x; 1.6450x over previous
//
#include <hip/hip_runtime.h>
#include <hip/hip_bf16.h>

// BailingMoeBlock: T=2048 H=1024 NH=8 NKV=2 HD=128 E=16 TOPK=4 NG=4 TKG=2 F=FS=1024
// Round 4: FFN GEMMs (shared + MoE expert) moved to bf16 MFMA (16x16x32),
// m97-style: 128x128 tile, BK=32, global_load_lds width=16, B^T bf16 weights
// (per-call cvt+transpose). Attention/QKV/dense/router stay fp32 to protect
// top-k expert selection. ws ~171 MiB with phase-checked aliasing.

#define T_TOK 2048
#define H_DIM 1024
#define NHEAD 8
#define NKVH 2
#define HDIM 128
#define QKV_DIM 1536
#define E_EXP 16
#define TOPKE 4
#define F_DIM 1024
#define FS_DIM 1024
#define NPAIR (T_TOK*TOPKE)
#define EPS_F 1e-6f

#define DEV __device__ __forceinline__

typedef __attribute__((ext_vector_type(4))) float f32x4;
typedef __attribute__((ext_vector_type(8))) short s16x8;

DEV float us2f(unsigned short u){ return __uint_as_float(((unsigned int)u)<<16); }
DEV unsigned short f2us(float f){
  __hip_bfloat16 b = __float2bfloat16(f);
  unsigned short u; __builtin_memcpy(&u,&b,2); return u;
}

DEV void gl2lds16(const void* g, void* l){
  __builtin_amdgcn_global_load_lds(
      (const __attribute__((address_space(1))) void*)g,
      (__attribute__((address_space(3))) void*)l, 16, 0, 0);
}

// ---- block reductions (256 threads = 4 waves) ----
DEV float bred_sum(float v, float* sm){
  #pragma unroll
  for(int o=32;o>0;o>>=1) v += __shfl_down(v,o);
  int w = threadIdx.x>>6, l = threadIdx.x&63;
  __syncthreads();
  if(l==0) sm[w]=v;
  __syncthreads();
  return sm[0]+sm[1]+sm[2]+sm[3];
}

// ---- weight cvt+transpose: out[z][n][k] = bf16(in[z][k][n]) ----
__global__ __launch_bounds__(256) void k_cvt_t(const float* __restrict__ in,
    unsigned short* __restrict__ out, int Kd, int Nd){
  const int z = blockIdx.z;
  const int kb = blockIdx.y*32, nb = blockIdx.x*32;
  __shared__ float Lt[32][33];
  const int tid = threadIdx.x;
  const int r = tid>>3, c4 = (tid&7)*4;
  const float* src = in + (long long)z*Kd*Nd + (long long)(kb+r)*Nd + nb + c4;
  float4 v = *(const float4*)src;
  Lt[r][c4+0]=v.x; Lt[r][c4+1]=v.y; Lt[r][c4+2]=v.z; Lt[r][c4+3]=v.w;
  __syncthreads();
  ushort4 o;
  o.x = f2us(Lt[c4+0][r]); o.y = f2us(Lt[c4+1][r]);
  o.z = f2us(Lt[c4+2][r]); o.w = f2us(Lt[c4+3][r]);
  *(ushort4*)(out + (long long)z*Nd*Kd + (long long)(nb+r)*Kd + kb + c4) = o;
}

// ---- MFMA GEMM: C[M x N](bf16) = A[M x K](bf16, opt gather) * Bt[N x K]^T ----
// 128x128 tile, BK=32, 256 threads (4 waves, each 64x64 = 4x4 frags).
template<bool GROUPED, bool GATHER>
__global__ __launch_bounds__(256) void gemm_mfma(
    const unsigned short* __restrict__ A, int lda,
    const unsigned short* __restrict__ Bt, int ldbt, long long bstride,
    unsigned short* __restrict__ C, int ldc,
    const int* __restrict__ rowidx, const int* __restrict__ grpoff,
    int Mdense, int K){
  const int z = blockIdx.z;
  const int rb = GROUPED ? grpoff[z] : 0;
  const int re = GROUPED ? grpoff[z+1] : Mdense;
  const int m0 = rb + blockIdx.y*128;
  if(m0 >= re) return;
  const int n0 = blockIdx.x*128;
  const unsigned short* Bz = Bt + (long long)z*bstride;

  __shared__ unsigned short As[128][32];   // [m][k] 8KB
  __shared__ unsigned short Bs[128][32];   // [n][k] 8KB

  const int tid = threadIdx.x;
  // staging: 512 slots of 16B per tile; slot s: row=s>>2, chunk=s&3 (8 bf16)
  // thread t covers slots t and t+256 (LDS dst = wave base + lane*16).
  const int s0 = tid, s1 = tid+256;
  int gr0 = m0 + (s0>>2), gr1 = m0 + (s1>>2);
  if(GROUPED){ gr0 = min(gr0, re-1); gr1 = min(gr1, re-1); }
  if(GATHER){ gr0 = rowidx[gr0]; gr1 = rowidx[gr1]; }
  const unsigned short* ag0 = A + (long long)gr0*lda + (s0&3)*8;
  const unsigned short* ag1 = A + (long long)gr1*lda + (s1&3)*8;
  const unsigned short* bg0 = Bz + (long long)(n0 + (s0>>2))*ldbt + (s0&3)*8;
  const unsigned short* bg1 = Bz + (long long)(n0 + (s1>>2))*ldbt + (s1&3)*8;
  char* asb = (char*)&As[0][0];
  char* bsb = (char*)&Bs[0][0];
  const int wb = (tid & 192)*16;           // wave's lane-0 byte offset

  const int w = tid>>6, lane = tid&63;
  const int wm = (w>>1)*64, wn = (w&1)*64;
  const int fr = lane&15, q8 = (lane>>4)*8;

  f32x4 zero = {0.f,0.f,0.f,0.f};
  f32x4 acc[4][4];
  #pragma unroll
  for(int mi=0;mi<4;mi++)
    #pragma unroll
    for(int ni=0;ni<4;ni++) acc[mi][ni]=zero;

  for(int k0=0;k0<K;k0+=32){
    __syncthreads();                        // prior readers done
    gl2lds16(ag0 + k0, asb + wb);
    gl2lds16(ag1 + k0, asb + 4096 + wb);
    gl2lds16(bg0 + k0, bsb + wb);
    gl2lds16(bg1 + k0, bsb + 4096 + wb);
    __syncthreads();                        // vmcnt(0) drain + barrier
    s16x8 af[4], bf[4];
    #pragma unroll
    for(int mi=0;mi<4;mi++) af[mi] = *(const s16x8*)&As[wm+mi*16+fr][q8];
    #pragma unroll
    for(int ni=0;ni<4;ni++) bf[ni] = *(const s16x8*)&Bs[wn+ni*16+fr][q8];
    #pragma unroll
    for(int mi=0;mi<4;mi++)
      #pragma unroll
      for(int ni=0;ni<4;ni++)
        acc[mi][ni] = __builtin_amdgcn_mfma_f32_16x16x32_bf16(af[mi], bf[ni], acc[mi][ni], 0,0,0);
  }
  // C/D: col = lane&15, row = (lane>>4)*4 + reg
  const int q4 = (lane>>4)*4;
  #pragma unroll
  for(int mi=0;mi<4;mi++)
    #pragma unroll
    for(int ni=0;ni<4;ni++){
      const int col = n0 + wn + ni*16 + fr;
      #pragma unroll
      for(int r=0;r<4;r++){
        const int row = m0 + wm + mi*16 + q4 + r;
        if(row < re) C[(long long)row*ldc + col] = f2us(acc[mi][ni][r]);
      }
    }
}

// ---- silu-mul: act[r][c] = silu(gu[r][c]) * gu[r][c+1024]; one block per row ----
__global__ __launch_bounds__(256) void k_silu(const unsigned short* __restrict__ gu,
    unsigned short* __restrict__ act){
  const int r = blockIdx.x, c = threadIdx.x*4;
  const ushort4 g4 = *(const ushort4*)(gu + (long long)r*2048 + c);
  const ushort4 u4 = *(const ushort4*)(gu + (long long)r*2048 + 1024 + c);
  float g[4] = {us2f(g4.x),us2f(g4.y),us2f(g4.z),us2f(g4.w)};
  float u[4] = {us2f(u4.x),us2f(u4.y),us2f(u4.z),us2f(u4.w)};
  ushort4 o;
  o.x = f2us((g[0]/(1.f+__expf(-g[0])))*u[0]);
  o.y = f2us((g[1]/(1.f+__expf(-g[1])))*u[1]);
  o.z = f2us((g[2]/(1.f+__expf(-g[2])))*u[2]);
  o.w = f2us((g[3]/(1.f+__expf(-g[3])))*u[3]);
  *(ushort4*)(act + (long long)r*1024 + c) = o;
}

// ---- K1: resid = hs + residual ; h = rmsnorm(resid, ln1_w) ----
__global__ __launch_bounds__(256) void k_add_rmsnorm(const float* __restrict__ hs,
    const float* __restrict__ rs, const float* __restrict__ w,
    float* __restrict__ resid, float* __restrict__ h){
  int t = blockIdx.x, tid = threadIdx.x;
  __shared__ float sm[4];
  const long base = (long)t*H_DIM;
  float x[4]; float ss = 0.f;
  #pragma unroll
  for(int i=0;i<4;i++){
    int c = tid + i*256;
    float v = hs[base+c] + rs[base+c];
    x[i]=v; resid[base+c]=v; ss += v*v;
  }
  float tot = bred_sum(ss, sm);
  float rms = rsqrtf(tot/(float)H_DIM + EPS_F);
  #pragma unroll
  for(int i=0;i<4;i++){
    int c = tid + i*256;
    h[base+c] = x[i]*rms*w[c];
  }
}

// ---- fp32 GEMM (QKV + dense only): C = A*B (+D) ----
template<int EPI_ADD>
__global__ __launch_bounds__(256) void gemm_f32(
    const float* __restrict__ A, int lda,
    const float* __restrict__ B, int ldb,
    float* __restrict__ C, int ldc,
    const float* __restrict__ D, int M, int K){
  const int m0 = blockIdx.y*128;
  const int n0 = blockIdx.x*64;
  __shared__ float As[16][132];
  __shared__ float Bs[16][65];
  float acc[8][4];
  #pragma unroll
  for(int i=0;i<8;i++)
    #pragma unroll
    for(int j=0;j<4;j++) acc[i][j]=0.f;
  const int tid = threadIdx.x;
  const int tx = tid & 15, ty = tid >> 4;
  const int ar = tid >> 1, ac = (tid & 1)*8;
  const int brr = tid >> 4, bc = (tid & 15)*4;
  const float* Aptr = A + (long long)(m0+ar)*lda;
  for(int k0=0;k0<K;k0+=16){
    float4 a0 = *(const float4*)(Aptr + k0 + ac);
    float4 a1 = *(const float4*)(Aptr + k0 + ac + 4);
    float4 bv = *(const float4*)(B + (long long)(k0+brr)*ldb + n0 + bc);
    __syncthreads();
    As[ac+0][ar]=a0.x; As[ac+1][ar]=a0.y; As[ac+2][ar]=a0.z; As[ac+3][ar]=a0.w;
    As[ac+4][ar]=a1.x; As[ac+5][ar]=a1.y; As[ac+6][ar]=a1.z; As[ac+7][ar]=a1.w;
    Bs[brr][bc+0]=bv.x; Bs[brr][bc+1]=bv.y; Bs[brr][bc+2]=bv.z; Bs[brr][bc+3]=bv.w;
    __syncthreads();
    #pragma unroll
    for(int kk=0;kk<16;kk++){
      float a[8], b[4];
      #pragma unroll
      for(int i=0;i<8;i++) a[i]=As[kk][ty*8+i];
      #pragma unroll
      for(int j=0;j<4;j++) b[j]=Bs[kk][tx*4+j];
      #pragma unroll
      for(int i=0;i<8;i++)
        #pragma unroll
        for(int j=0;j<4;j++) acc[i][j] = fmaf(a[i], b[j], acc[i][j]);
    }
  }
  #pragma unroll
  for(int i=0;i<8;i++){
    int r = m0 + ty*8 + i;
    float* crow = C + (long long)r*ldc + n0 + tx*4;
    float4 v = make_float4(acc[i][0],acc[i][1],acc[i][2],acc[i][3]);
    if(EPI_ADD){
      const float4 d = *(const float4*)(D + (long long)r*ldc + n0 + tx*4);
      v.x+=d.x; v.y+=d.y; v.z+=d.z; v.w+=d.w;
    }
    *(float4*)crow = v;
  }
}

// ---- K3: per-(t,slot) q/k rmsnorm + rope, v copy. 64 threads. ----
__global__ __launch_bounds__(64) void k_qkv_post(const float* __restrict__ qkv,
    const float* __restrict__ qw, const float* __restrict__ kw,
    const int* __restrict__ pos,
    float* __restrict__ qb, float* __restrict__ kb, float* __restrict__ vb){
  int slot = blockIdx.x, t = blockIdx.y, lane = threadIdx.x;
  const float* x = qkv + (long long)t*QKV_DIM + slot*HDIM;
  float x0 = x[lane], x1 = x[lane+64];
  if(slot < 10){
    float ss = x0*x0 + x1*x1;
    #pragma unroll
    for(int o=32;o>0;o>>=1) ss += __shfl_xor(ss,o);
    float rms = rsqrtf(ss/(float)HDIM + EPS_F);
    const float* w = (slot<8)? qw : kw;
    float n0 = x0*rms*w[lane];
    float n1 = x1*rms*w[lane+64];
    float p = (float)pos[t];
    float invf = __expf(-((float)lane/64.f)*9.210340371976184f);
    float ang = p*invf;
    float s = sinf(ang), c = cosf(ang);
    float o0 = n0*c - n1*s;
    float o1 = n1*c + n0*s;
    float* dst = (slot<8)? (qb + ((long long)slot*T_TOK + t)*HDIM)
                         : (kb + ((long long)(slot-8)*T_TOK + t)*HDIM);
    dst[lane]=o0; dst[lane+64]=o1;
  } else {
    float* dst = vb + ((long long)(slot-10)*T_TOK + t)*HDIM;
    dst[lane]=x0; dst[lane+64]=x1;
  }
}

// ---- K4: flash attention (fp32) ----
#define BQ 32
#define BK 64
__global__ __launch_bounds__(256) void k_flash(const float* __restrict__ qb,
    const float* __restrict__ kb, const float* __restrict__ vb,
    float* __restrict__ ctx){
  const int h = blockIdx.x, pair = blockIdx.y;
  const int kv = h >> 2;
  const int tid = threadIdx.x;
  const int tx = tid & 15, ty = tid >> 4;
  __shared__ float Qs[HDIM][34];
  __shared__ float Ks[HDIM][68];
  __shared__ float Vs[BK][HDIM];
  __shared__ float Ps[BK][34];
  const float scale = 0.08838834764831845f;

  for(int which=0; which<2; which++){
    const int qt = which ? (63 - pair) : pair;
    const int q0 = qt * BQ;
    {
      int r = tid >> 3, cb = (tid & 7) * 16;
      const float* src = qb + ((long long)h*T_TOK + q0 + r)*HDIM + cb;
      #pragma unroll
      for(int j4=0;j4<4;j4++){
        float4 v4 = *(const float4*)(src + j4*4);
        Qs[cb+j4*4+0][r]=v4.x; Qs[cb+j4*4+1][r]=v4.y;
        Qs[cb+j4*4+2][r]=v4.z; Qs[cb+j4*4+3][r]=v4.w;
      }
    }
    float m0=-1e30f, m1=-1e30f, l0=0.f, l1=0.f;
    float O0[8], O1[8];
    #pragma unroll
    for(int j=0;j<8;j++){ O0[j]=0.f; O1[j]=0.f; }
    const int nkt = (qt>>1) + 1;
    for(int kt=0; kt<nkt; kt++){
      const int k0 = kt*BK;
      __syncthreads();
      {
        int r = tid >> 2, cb = (tid & 3) * 32;
        const float* ks = kb + ((long long)kv*T_TOK + k0 + r)*HDIM + cb;
        const float* vs = vb + ((long long)kv*T_TOK + k0 + r)*HDIM + cb;
        #pragma unroll
        for(int j4=0;j4<8;j4++){
          float4 v4 = *(const float4*)(ks + j4*4);
          Ks[cb+j4*4+0][r]=v4.x; Ks[cb+j4*4+1][r]=v4.y;
          Ks[cb+j4*4+2][r]=v4.z; Ks[cb+j4*4+3][r]=v4.w;
          *(float4*)(&Vs[r][cb+j4*4]) = *(const float4*)(vs + j4*4);
        }
      }
      __syncthreads();
      float s00=0,s01=0,s02=0,s03=0,s10=0,s11=0,s12=0,s13=0;
      const float* qsp = &Qs[0][ty*2];
      const float* ksp = &Ks[0][tx*4];
      #pragma unroll 4
      for(int kk=0;kk<HDIM;kk++){
        float2 q2 = *(const float2*)(qsp + kk*34);
        float4 k4 = *(const float4*)(ksp + kk*68);
        s00=fmaf(q2.x,k4.x,s00); s01=fmaf(q2.x,k4.y,s01);
        s02=fmaf(q2.x,k4.z,s02); s03=fmaf(q2.x,k4.w,s03);
        s10=fmaf(q2.y,k4.x,s10); s11=fmaf(q2.y,k4.y,s11);
        s12=fmaf(q2.y,k4.z,s12); s13=fmaf(q2.y,k4.w,s13);
      }
      float s[2][4] = {{s00*scale,s01*scale,s02*scale,s03*scale},
                       {s10*scale,s11*scale,s12*scale,s13*scale}};
      if(kt == nkt-1){
        #pragma unroll
        for(int qi=0;qi<2;qi++)
          #pragma unroll
          for(int ki=0;ki<4;ki++)
            if(k0 + tx*4 + ki > q0 + ty*2 + qi) s[qi][ki] = -1e30f;
      }
      float rm0 = fmaxf(fmaxf(s[0][0],s[0][1]),fmaxf(s[0][2],s[0][3]));
      float rm1 = fmaxf(fmaxf(s[1][0],s[1][1]),fmaxf(s[1][2],s[1][3]));
      #pragma unroll
      for(int o=1;o<16;o<<=1){
        rm0 = fmaxf(rm0, __shfl_xor(rm0,o));
        rm1 = fmaxf(rm1, __shfl_xor(rm1,o));
      }
      float mn0 = fmaxf(m0, rm0), mn1 = fmaxf(m1, rm1);
      float a0 = __expf(m0-mn0), a1 = __expf(m1-mn1);
      float p[2][4]; float rs0=0.f, rs1=0.f;
      #pragma unroll
      for(int ki=0;ki<4;ki++){
        p[0][ki] = __expf(s[0][ki]-mn0); rs0 += p[0][ki];
        p[1][ki] = __expf(s[1][ki]-mn1); rs1 += p[1][ki];
      }
      #pragma unroll
      for(int o=1;o<16;o<<=1){
        rs0 += __shfl_xor(rs0,o);
        rs1 += __shfl_xor(rs1,o);
      }
      l0 = l0*a0 + rs0; l1 = l1*a1 + rs1;
      m0 = mn0; m1 = mn1;
      #pragma unroll
      for(int j=0;j<8;j++){ O0[j]*=a0; O1[j]*=a1; }
      #pragma unroll
      for(int ki=0;ki<4;ki++){
        Ps[tx*4+ki][ty*2+0] = p[0][ki];
        Ps[tx*4+ki][ty*2+1] = p[1][ki];
      }
      __syncthreads();
      const float* vsp = &Vs[0][tx*8];
      const float* psp = &Ps[0][ty*2];
      #pragma unroll 2
      for(int k=0;k<BK;k++){
        float2 pf = *(const float2*)(psp + k*34);
        float4 va = *(const float4*)(vsp + k*HDIM);
        float4 vb4 = *(const float4*)(vsp + k*HDIM + 4);
        O0[0]=fmaf(pf.x,va.x,O0[0]); O0[1]=fmaf(pf.x,va.y,O0[1]);
        O0[2]=fmaf(pf.x,va.z,O0[2]); O0[3]=fmaf(pf.x,va.w,O0[3]);
        O0[4]=fmaf(pf.x,vb4.x,O0[4]); O0[5]=fmaf(pf.x,vb4.y,O0[5]);
        O0[6]=fmaf(pf.x,vb4.z,O0[6]); O0[7]=fmaf(pf.x,vb4.w,O0[7]);
        O1[0]=fmaf(pf.y,va.x,O1[0]); O1[1]=fmaf(pf.y,va.y,O1[1]);
        O1[2]=fmaf(pf.y,va.z,O1[2]); O1[3]=fmaf(pf.y,va.w,O1[3]);
        O1[4]=fmaf(pf.y,vb4.x,O1[4]); O1[5]=fmaf(pf.y,vb4.y,O1[5]);
        O1[6]=fmaf(pf.y,vb4.z,O1[6]); O1[7]=fmaf(pf.y,vb4.w,O1[7]);
      }
    }
    float inv0 = 1.f/l0, inv1 = 1.f/l1;
    float* dst0 = ctx + ((long long)(q0+ty*2))*(NHEAD*HDIM) + h*HDIM + tx*8;
    float* dst1 = dst0 + NHEAD*HDIM;
    float4 o;
    o = make_float4(O0[0]*inv0,O0[1]*inv0,O0[2]*inv0,O0[3]*inv0); *(float4*)dst0 = o;
    o = make_float4(O0[4]*inv0,O0[5]*inv0,O0[6]*inv0,O0[7]*inv0); *(float4*)(dst0+4) = o;
    o = make_float4(O1[0]*inv1,O1[1]*inv1,O1[2]*inv1,O1[3]*inv1); *(float4*)dst1 = o;
    o = make_float4(O1[4]*inv1,O1[5]*inv1,O1[6]*inv1,O1[7]*inv1); *(float4*)(dst1+4) = o;
  }
}

// ---- K6: read resid2 (=out1), write h2f (fp32, router) + h2b (bf16, GEMM A) ----
__global__ __launch_bounds__(256) void k_rms2(const float* __restrict__ r2,
    const float* __restrict__ w, float* __restrict__ h2f,
    unsigned short* __restrict__ h2b){
  int t = blockIdx.x, tid = threadIdx.x;
  __shared__ float sm[4];
  const long base = (long)t*H_DIM;
  float x[4]; float ss=0.f;
  #pragma unroll
  for(int i=0;i<4;i++){
    int c = tid+i*256;
    float v = r2[base+c];
    x[i]=v; ss += v*v;
  }
  float tot = bred_sum(ss, sm);
  float rms = rsqrtf(tot/(float)H_DIM + EPS_F);
  #pragma unroll
  for(int i=0;i<4;i++){
    int c = tid+i*256;
    float v = x[i]*rms*w[c];
    h2f[base+c] = v;
    h2b[base+c] = f2us(v);
  }
}

// ---- K7: router (fp32 exact) ----
__global__ __launch_bounds__(256) void k_router(const float* __restrict__ h2,
    const float* __restrict__ gw, const float* __restrict__ eb,
    int* __restrict__ topk_idx, float* __restrict__ topk_w, int* __restrict__ counts){
  int t = blockIdx.x, tid = threadIdx.x;
  int e = tid & 15, seg = tid >> 4;
  const float* hrow = h2 + (long long)t*H_DIM;
  float part = 0.f;
  #pragma unroll 4
  for(int i=0;i<64;i++){
    int hh = seg*64 + i;
    part += hrow[hh]*gw[hh*E_EXP + e];
  }
  __shared__ float pm[16][17];
  __shared__ float sS[16], sfc[16];
  pm[seg][e] = part;
  __syncthreads();
  if(tid < 16){
    float l = 0.f;
    #pragma unroll
    for(int s=0;s<16;s++) l += pm[s][tid];
    float sg = 1.f/(1.f+expf(-l));
    sS[tid]=sg; sfc[tid]=sg+eb[tid];
  }
  __syncthreads();
  if(tid==0){
    float gs[4];
    #pragma unroll
    for(int g=0; g<4; g++){
      float m1=-1e30f, m2=-1e30f;
      for(int j=0;j<4;j++){
        float v=sfc[g*4+j];
        if(v>m1){ m2=m1; m1=v; } else if(v>m2){ m2=v; }
      }
      gs[g]=m1+m2;
    }
    int g1=0; for(int g=1;g<4;g++) if(gs[g]>gs[g1]) g1=g;
    int g2=-1; for(int g=0;g<4;g++){ if(g==g1) continue; if(g2<0||gs[g]>gs[g2]) g2=g; }
    bool taken[16];
    #pragma unroll
    for(int i=0;i<16;i++) taken[i]=false;
    int idx[4];
    for(int j=0;j<4;j++){
      int best=-1; float bv=-1e30f;
      for(int i=0;i<16;i++){
        int g=i>>2;
        if(g!=g1 && g!=g2) continue;
        if(taken[i]) continue;
        if(best<0 || sfc[i]>bv){ best=i; bv=sfc[i]; }
      }
      taken[best]=true; idx[j]=best;
    }
    float w[4]; float s=0.f;
    #pragma unroll
    for(int j=0;j<4;j++){ w[j]=sS[idx[j]]; s+=w[j]; }
    s += 1e-20f;
    #pragma unroll
    for(int j=0;j<4;j++){
      topk_idx[t*4+j]=idx[j];
      topk_w[t*4+j]=w[j]/s;
      atomicAdd(&counts[idx[j]],1);
    }
  }
}

__global__ void k_zero(int* __restrict__ counts){ if(threadIdx.x<16) counts[threadIdx.x]=0; }

__global__ void k_scan(const int* __restrict__ counts, int* __restrict__ offs, int* __restrict__ cursor){
  if(threadIdx.x==0){
    int s=0;
    for(int e2=0;e2<16;e2++){ offs[e2]=s; cursor[e2]=s; s+=counts[e2]; }
    offs[16]=s;
  }
}

__global__ __launch_bounds__(256) void k_scatter(const int* __restrict__ topk_idx,
    int* __restrict__ cursor, int* __restrict__ pair_tok, int* __restrict__ tok2pair){
  int i = blockIdx.x*256 + threadIdx.x;
  int e = topk_idx[i];
  int pos = atomicAdd(&cursor[e],1);
  pair_tok[pos] = i>>2;
  tok2pair[i] = pos;
}

// ---- K15: out0 = sum_j 2*w_j*y[pair_j] + shared (bf16 in, fp32 out) ----
__global__ __launch_bounds__(256) void k_combine(const unsigned short* __restrict__ y,
    const unsigned short* __restrict__ sout, const int* __restrict__ tok2pair,
    const float* __restrict__ topk_w, float* __restrict__ out0){
  int t = blockIdx.x, tid = threadIdx.x;
  int p[4]; float w[4];
  #pragma unroll
  for(int j=0;j<4;j++){ p[j]=tok2pair[t*4+j]; w[j]=topk_w[t*4+j]*2.0f; }
  const long base = (long)t*H_DIM;
  #pragma unroll
  for(int i=0;i<4;i++){
    int c = tid + i*256;
    float v = us2f(sout[base+c]);
    #pragma unroll
    for(int j=0;j<4;j++) v += w[j]*us2f(y[(long long)p[j]*H_DIM + c]);
    out0[base+c] = v;
  }
}

extern "C" void kernel_launch(void* const* d_in, const int* in_sizes, int n_in,
                              void* d_out, int out_size, void* d_ws, size_t ws_size,
                              hipStream_t stream) {
  const float* hs   = (const float*)d_in[0];
  const float* rsd  = (const float*)d_in[1];
  const int*   pos  = (const int*)d_in[2];
  const float* ln1  = (const float*)d_in[3];
  const float* qkvw = (const float*)d_in[4];
  const float* qnw  = (const float*)d_in[5];
  const float* knw  = (const float*)d_in[6];
  const float* dw   = (const float*)d_in[7];
  const float* ln2  = (const float*)d_in[8];
  const float* gw   = (const float*)d_in[9];
  const float* eb   = (const float*)d_in[10];
  const float* w13  = (const float*)d_in[11];
  const float* w2   = (const float*)d_in[12];
  const float* wsgu = (const float*)d_in[13];
  const float* wsd  = (const float*)d_in[14];
  float* out0 = (float*)d_out;
  float* out1 = out0 + (size_t)T_TOK*H_DIM;   // resid2

  char* W = (char*)d_ws;
  // byte offsets (phase-checked aliasing; see journal):
  float* resid = (float*)(W + 0);                       // [A..E]; sact aliases
  float* h     = (float*)(W + 8388608);                 // h [A..B], ctx [D..E]
  float* ctx   = h;
  float* qkv   = (float*)(W + 16777216);                // [B..C]; sgu aliases
  float* qb    = (float*)(W + 29360128);                // [C..D]
  float* h2f   = (float*)(W + 37748736);                // [F..G]
  float* kb    = (float*)(W + 46137344);                // [C..D]; sout aliases
  float* vb    = (float*)(W + 48234496);
  unsigned short* gu    = (unsigned short*)(W + 8388608);   // [I1..I2] (33.5MB over dead h/qkv/qb/h2f)
  unsigned short* ybuf  = (unsigned short*)(W + 8388608);   // [I3..K] (gu dead)
  unsigned short* sgu   = (unsigned short*)(W + 16777216);  // [H1] (qkv dead)
  unsigned short* sact  = (unsigned short*)(W + 0);         // [H1b..H2] (resid dead)
  unsigned short* sout  = (unsigned short*)(W + 46137344);  // [H2..K] (kb/vb dead)
  unsigned short* h2b   = (unsigned short*)(W + 50331648);  // [F..I1]
  unsigned short* act   = (unsigned short*)(W + 54525952);  // [I2..I3]
  unsigned short* w13t  = (unsigned short*)(W + 71303168);  // persistent
  unsigned short* w2t   = (unsigned short*)(W + 138412032);
  unsigned short* wsgut = (unsigned short*)(W + 171966464);
  unsigned short* wsdt  = (unsigned short*)(W + 176160768);
  float* topkw = (float*)(W + 178257920);
  int* topki   = (int*)(W + 178290688);
  int* ptok    = (int*)(W + 178323456);
  int* t2p     = (int*)(W + 178356224);
  int* cnt     = (int*)(W + 178388992);
  int* offs    = (int*)(W + 178389056);
  int* cur     = (int*)(W + 178389184);

  // 0. weight cvt + transpose -> bf16 B^T
  k_cvt_t<<<dim3(64,32,16), 256, 0, stream>>>(w13,  w13t,  1024, 2048);
  k_cvt_t<<<dim3(32,32,16), 256, 0, stream>>>(w2,   w2t,   1024, 1024);
  k_cvt_t<<<dim3(64,32,1),  256, 0, stream>>>(wsgu, wsgut, 1024, 2048);
  k_cvt_t<<<dim3(32,32,1),  256, 0, stream>>>(wsd,  wsdt,  1024, 1024);
  // A. resid + rmsnorm
  k_add_rmsnorm<<<T_TOK, 256, 0, stream>>>(hs, rsd, ln1, resid, h);
  // B. qkv = h @ qkv_w (fp32)
  gemm_f32<0><<<dim3(QKV_DIM/64, T_TOK/128), 256, 0, stream>>>(
      h, H_DIM, qkvw, QKV_DIM, qkv, QKV_DIM, nullptr, T_TOK, H_DIM);
  // C. q/k norm + rope
  k_qkv_post<<<dim3(12, T_TOK), 64, 0, stream>>>(qkv, qnw, knw, pos, qb, kb, vb);
  // D. flash attention
  k_flash<<<dim3(NHEAD, T_TOK/BQ/2), 256, 0, stream>>>(qb, kb, vb, ctx);
  // E. resid2 = ctx @ dense_w + resid -> out1 (fp32)
  gemm_f32<1><<<dim3(H_DIM/64, T_TOK/128), 256, 0, stream>>>(
      ctx, NHEAD*HDIM, dw, H_DIM, out1, H_DIM, resid, T_TOK, NHEAD*HDIM);
  // F. h2 = rmsnorm(out1)
  k_rms2<<<T_TOK, 256, 0, stream>>>(out1, ln2, h2f, h2b);
  // G. router (fp32 h2 -> selection unchanged vs round 3)
  k_zero<<<1, 64, 0, stream>>>(cnt);
  k_router<<<T_TOK, 256, 0, stream>>>(h2f, gw, eb, topki, topkw, cnt);
  k_scan<<<1, 64, 0, stream>>>(cnt, offs, cur);
  k_scatter<<<NPAIR/256, 256, 0, stream>>>(topki, cur, ptok, t2p);
  // H. shared expert (MFMA)
  gemm_mfma<false,false><<<dim3(16,16,1), 256, 0, stream>>>(
      h2b, 1024, wsgut, 1024, 0, sgu, 2048, nullptr, nullptr, T_TOK, 1024);
  k_silu<<<T_TOK, 256, 0, stream>>>(sgu, sact);
  gemm_mfma<false,false><<<dim3(8,16,1), 256, 0, stream>>>(
      sact, 1024, wsdt, 1024, 0, sout, 1024, nullptr, nullptr, T_TOK, 1024);
  // I. MoE expert FFN (MFMA, grouped)
  gemm_mfma<true,true><<<dim3(16,64,16), 256, 0, stream>>>(
      h2b, 1024, w13t, 1024, (long long)2048*1024, gu, 2048, ptok, offs, 0, 1024);
  k_silu<<<NPAIR, 256, 0, stream>>>(gu, act);
  gemm_mfma<true,false><<<dim3(8,64,16), 256, 0, stream>>>(
      act, 1024, w2t, 1024, (long long)1024*1024, ybuf, 1024, nullptr, offs, 0, 1024);
  // K. combine -> out0
  k_combine<<<T_TOK, 256, 0, stream>>>(ybuf, sout, t2p, topkw, out0);
}